// Round 10
// baseline (235.243 us; speedup 1.0000x reference)
//
#include <hip/hip_runtime.h>

#define KDIM 768
#define MANS 640      // L*B*T
#define VV   30000
#define NGRP 235      // ceil(30000/128)
#define NKS  (KDIM / 64)                   // 12 k-steps
#define NT   938                           // ceil(30000/32) vocab row-tiles
#define CVTBLK (NT * NKS)                  // 11256 cvt blocks: one (nt,kt) each
#define A2BLK  ((MANS / 64) * (KDIM / 128))  // 60 gemm blocks

typedef __attribute__((ext_vector_type(4)))  float  f32x4;
typedef __attribute__((ext_vector_type(16))) float  f32x16;
typedef __attribute__((ext_vector_type(8)))  __bf16 bf16x8;
typedef __attribute__((ext_vector_type(8)))  unsigned short ushort8;

// native f32->bf16 (RNE via v_cvt_pk_bf16_f32; compiler packs pairs — m240)
__device__ __forceinline__ unsigned short f2bf(float f) {
    union { __bf16 h; unsigned short u; } t;
    t.h = (__bf16)f;
    return t.u;
}

__device__ __forceinline__ ushort8 cvt8(f32x4 a, f32x4 b) {
    union { bf16x8 h; ushort8 u; } c;
    c.h[0] = (__bf16)a.x; c.h[1] = (__bf16)a.y;
    c.h[2] = (__bf16)a.z; c.h[3] = (__bf16)a.w;
    c.h[4] = (__bf16)b.x; c.h[5] = (__bf16)b.y;
    c.h[6] = (__bf16)b.z; c.h[7] = (__bf16)b.w;
    return c.u;
}

__device__ __forceinline__ void load_lds16(const unsigned short* g, unsigned short* l) {
    __builtin_amdgcn_global_load_lds(
        (__attribute__((address_space(1))) void*)(void*)g,
        (__attribute__((address_space(3))) void*)l,
        16, 0, 0);
}

// A2F fragment layout (written by gemm_a2, read by gemm_big):
//   off = (16*(mb*12+kt) + 4*(2*wm+fm) + g)*512 + lane*8  [lane=(halfb,colm)]
__device__ __forceinline__ long a2f_off(int m, int n) {
    int mb = m >> 7, wm = (m >> 6) & 1, fm = (m >> 5) & 1, colm = m & 31;
    int kt = n >> 6, g = (n >> 4) & 3, halfb = (n >> 3) & 1, e = n & 7;
    return ((((long)(mb * 12 + kt) * 2 + wm) * 2 + fm) * 4 + g) * 512
         + (halfb * 32 + colm) * 8 + e;
}

// VF fragment layout: element (v,k): nt=v>>5, colv=v&31, kt=k>>6, g=(k>>4)&3,
// hb=(k>>3)&1, e=k&7; off = (((nt*12+kt)*4+g)*64 + hb*32 + colv)*8 + e.
// Wave read at base+lane*8 = exact mfma_32x32x16 B-fragment.
// nt stride 24576, kt stride 2048, g stride 512 (ushorts).

// ===================== prep_small =====================
__global__ __launch_bounds__(256) void prep_small(
    const float* __restrict__ W, const float* __restrict__ A,
    const float* __restrict__ b, unsigned short* __restrict__ Wt_bf,
    float* __restrict__ cvec)
{
    __shared__ float ts[64][65];
    const int blk = blockIdx.x;
    if (blk < 144) {
        int bx = (blk % 12) * 64, by = (blk / 12) * 64;
        int tx = threadIdx.x & 63, tg = threadIdx.x >> 6;
#pragma unroll
        for (int i = 0; i < 16; ++i) {
            int r = tg * 16 + i;
            ts[r][tx] = W[(long)(by + r) * KDIM + bx + tx];
        }
        __syncthreads();
#pragma unroll
        for (int i = 0; i < 16; ++i) {
            int r = tg * 16 + i;
            Wt_bf[(long)(bx + r) * KDIM + by + tx] = f2bf(ts[tx][r]);
        }
    } else {
        int row  = (blk - 144) * 4 + (threadIdx.x >> 6);
        int lane = threadIdx.x & 63;
        const float* ap = A + (long)row * KDIM;
        float s = 0.f;
#pragma unroll
        for (int i = 0; i < KDIM / 64; ++i) s += ap[i * 64 + lane] * b[i * 64 + lane];
#pragma unroll
        for (int off = 32; off; off >>= 1) s += __shfl_down(s, off, 64);
        if (lane == 0) cvec[row] = s;
    }
}

// ===================== a2 gemm + vocab->VF cvt (fused grid) =====================
// blocks [0,60):            A2F = answer @ W (bf16), single-buffer LDS.
// blocks [60,60+11256):     one block = one (nt,kt): vocab f32 -> VF bf16.
//   Linear 1KB/wave writes; reads 32B/lane pair-merged.
__global__ __launch_bounds__(256) void gemm_a2(
    const float* __restrict__ Af, const unsigned short* __restrict__ Bp,
    unsigned short* __restrict__ outp,
    const float* __restrict__ vocab, unsigned short* __restrict__ vocab_vf)
{
    if (blockIdx.x >= A2BLK) {
        const int bid  = blockIdx.x - A2BLK;       // 0..11255 = nt*12 + kt
        const int nt   = bid / NKS;
        const int kt   = bid % NKS;
        const int t    = threadIdx.x;
        const int colv = t & 31;
        const int hb   = (t >> 5) & 1;
        const int g    = t >> 6;
        long row = (long)nt * 32 + colv;
        if (row > VV - 1) row = VV - 1;            // clamp tail rows (nt=937)
        const float* src = vocab + row * KDIM + kt * 64 + g * 16 + hb * 8;
        f32x4 v0 = ((const f32x4*)src)[0], v1 = ((const f32x4*)src)[1];
        long off = ((long)bid * 4 + g) * 512 + hb * 256 + colv * 8;
        *(ushort8*)(vocab_vf + off) = cvt8(v0, v1);
        return;
    }

    constexpr int TM = 64, TN = 128;
    __shared__ unsigned short sA[TM * 64];   // 8 KB
    __shared__ unsigned short sB[TN * 64];   // 16 KB

    const int t    = threadIdx.x;
    const int lane = t & 63;
    const int w    = t >> 6;
    const int wm   = w >> 1;
    const int wn   = w & 1;
    const int half = lane >> 5;
    const int col  = lane & 31;
    const long m0  = (long)(blockIdx.x % (MANS / 64)) * TM;
    const long n0  = (long)(blockIdx.x / (MANS / 64)) * TN;

    f32x16 acc[2];
    acc[0] = (f32x16)(0.f);
    acc[1] = (f32x16)(0.f);

    const float* gaf[2]; int laOff[2];
#pragma unroll
    for (int j = 0; j < 2; ++j) {
        int s   = (j * 4 + w) * 64 + lane;
        int row = s >> 3;
        int c   = (s & 7) ^ (row & 7);
        gaf[j]   = Af + (m0 + row) * KDIM + c * 8;
        laOff[j] = s * 8;
    }
    const unsigned short* gb[4]; unsigned short* lbB[4];
#pragma unroll
    for (int j = 0; j < 4; ++j) {
        int s   = (j * 4 + w) * 64 + lane;
        int row = s >> 3;
        int c   = (s & 7) ^ (row & 7);
        gb[j]  = Bp + (n0 + row) * KDIM + c * 8;
        lbB[j] = &sB[(j * 4 + w) * 64 * 8];
    }

    for (int k0 = 0; k0 < KDIM; k0 += 64) {
#pragma unroll
        for (int j = 0; j < 4; ++j) load_lds16(gb[j] + k0, lbB[j]);
#pragma unroll
        for (int j = 0; j < 2; ++j) {
            f32x4 v0 = ((const f32x4*)(gaf[j] + k0))[0];
            f32x4 v1 = ((const f32x4*)(gaf[j] + k0))[1];
            *(ushort8*)(&sA[0] + laOff[j]) = cvt8(v0, v1);
        }
        __syncthreads();

#pragma unroll
        for (int g = 0; g < 4; ++g) {
            const int cg = g * 2 + half;
            int arow = wm * 32 + col;
            bf16x8 af = *(const bf16x8*)&sA[(arow * 8 + (cg ^ (arow & 7))) * 8];
#pragma unroll
            for (int fn = 0; fn < 2; ++fn) {
                int brow = wn * 64 + fn * 32 + col;
                bf16x8 bfv = *(const bf16x8*)&sB[(brow * 8 + (cg ^ (brow & 7))) * 8];
                acc[fn] = __builtin_amdgcn_mfma_f32_32x32x16_bf16(
                    af, bfv, acc[fn], 0, 0, 0);
            }
        }
        __syncthreads();
    }

#pragma unroll
    for (int fn = 0; fn < 2; ++fn) {
        int n = (int)n0 + wn * 64 + fn * 32 + col;
#pragma unroll
        for (int rg = 0; rg < 16; ++rg) {
            int m = (int)m0 + wm * 32 + (rg & 3) + 8 * (rg >> 2) + 4 * half;
            outp[a2f_off(m, n)] = f2bf(acc[fn][rg]);
        }
    }
}

// ===================== big gemm: out = A2F @ VF^T + c =====================
// R9 dataflow K-loop UNCHANGED (4 structures all hit ~56us -> K-loop side is
// not the binder). NEW: store-path overhaul — the one invariant never tested.
//   (1) LDS-bounce epilogue: each wave transposes its 64x64 f32 tile through a
//       private 8KB LDS region (32 KB total) so stores are per-lane dwordx4
//       with 16-lane 256B-contiguous segments (was 64 dword stores of 2x128B).
//   (2) __builtin_nontemporal_store: 77 MB output bypasses L2 -> stops
//       evicting VF/A2F operand panels (suspected source of the 31 MB HBM
//       FETCH of L3-resident data and of effective ~1.4 TB/s write BW).
__global__ __launch_bounds__(256, 2) void gemm_big(
    const unsigned short* __restrict__ A, const unsigned short* __restrict__ VF,
    const float* __restrict__ cvec, float* __restrict__ outp)
{
    __shared__ float swz[4][2048];   // per-wave 8 KB bounce buffer (32 KB)

    const int id    = blockIdx.x;
    const int x     = id & 7;
    const int q     = id >> 3;
    const int m_idx = q % 5;
    const int n_grp = (q / 5) * 8 + x;
    if (n_grp >= NGRP) return;               // 25 pad blocks idle

    const int t    = threadIdx.x;
    const int lane = t & 63;
    const int w    = t >> 6;
    const int wm   = w >> 1;
    const int wn   = w & 1;
    const int half = lane >> 5;
    const int col  = lane & 31;
    const long n0  = (long)n_grp * 128;

    f32x16 acc[2][2];
#pragma unroll
    for (int i = 0; i < 2; ++i)
#pragma unroll
        for (int j = 0; j < 2; ++j) acc[i][j] = (f32x16)(0.f);

    // A: kt stride 8192, fm stride 2048, g stride 512 (ushorts)
    const unsigned short* aB = A + ((long)16 * (m_idx * 12) + 8 * wm) * 512
                                 + lane * 8;
    // B: per-fn base, nt clamped to 937 (tail n-tiles; stores guarded)
    int nt0 = n_grp * 4 + wn * 2;     if (nt0 > NT - 1) nt0 = NT - 1;
    int nt1 = n_grp * 4 + wn * 2 + 1; if (nt1 > NT - 1) nt1 = NT - 1;
    const unsigned short* bB0 = VF + (long)nt0 * 24576 + lane * 8;
    const unsigned short* bB1 = VF + (long)nt1 * 24576 + lane * 8;

    bf16x8 fa[2][2][4];   // [buf][fm][g]
    bf16x8 fb[2][2][4];   // [buf][fn][g]

    // prologue: load kt=0 into buf 0
#pragma unroll
    for (int g = 0; g < 4; ++g) {
        fa[0][0][g] = *(const bf16x8*)(aB + g * 512);
        fa[0][1][g] = *(const bf16x8*)(aB + 2048 + g * 512);
        fb[0][0][g] = *(const bf16x8*)(bB0 + g * 512);
        fb[0][1][g] = *(const bf16x8*)(bB1 + g * 512);
    }

#pragma unroll
    for (int kt = 0; kt < NKS; ++kt) {
        const int cur = kt & 1, nxt = cur ^ 1;
        if (kt < NKS - 1) {                  // prefetch kt+1
            const unsigned short* aK  = aB  + (long)(kt + 1) * 8192;
            const unsigned short* bK0 = bB0 + (long)(kt + 1) * 2048;
            const unsigned short* bK1 = bB1 + (long)(kt + 1) * 2048;
#pragma unroll
            for (int g = 0; g < 4; ++g) {
                fa[nxt][0][g] = *(const bf16x8*)(aK + g * 512);
                fa[nxt][1][g] = *(const bf16x8*)(aK + 2048 + g * 512);
                fb[nxt][0][g] = *(const bf16x8*)(bK0 + g * 512);
                fb[nxt][1][g] = *(const bf16x8*)(bK1 + g * 512);
            }
        }
#pragma unroll
        for (int g = 0; g < 4; ++g) {
            acc[0][0] = __builtin_amdgcn_mfma_f32_32x32x16_bf16(
                fa[cur][0][g], fb[cur][0][g], acc[0][0], 0, 0, 0);
            acc[0][1] = __builtin_amdgcn_mfma_f32_32x32x16_bf16(
                fa[cur][0][g], fb[cur][1][g], acc[0][1], 0, 0, 0);
            acc[1][0] = __builtin_amdgcn_mfma_f32_32x32x16_bf16(
                fa[cur][1][g], fb[cur][0][g], acc[1][0], 0, 0, 0);
            acc[1][1] = __builtin_amdgcn_mfma_f32_32x32x16_bf16(
                fa[cur][1][g], fb[cur][1][g], acc[1][1], 0, 0, 0);
        }
    }

    // ---- store-path epilogue: LDS-bounce + 256B-contiguous nontemporal ----
    float* ldsw = &swz[w][0];
    const long m_base = (long)m_idx * 128 + wm * 64;
    const long n_base = n0 + wn * 64;
    const int  rsub   = lane >> 4;
    const int  c4     = (lane & 15) * 4;
    const long nv     = n_base + c4;
    const bool nok    = (nv < VV);          // 4-aligned => exact per-lane guard

#pragma unroll
    for (int fm = 0; fm < 2; ++fm) {
        // scatter this fm-half (32 rows x 64 cols) into LDS, + cvec
#pragma unroll
        for (int fn = 0; fn < 2; ++fn) {
#pragma unroll
            for (int rg = 0; rg < 16; ++rg) {
                int  rl = (rg & 3) + 8 * (rg >> 2) + 4 * half;   // 0..31
                long m  = m_base + fm * 32 + rl;
                ldsw[rl * 64 + fn * 32 + col] = acc[fm][fn][rg] + cvec[m];
            }
        }
        // gather 4 rows x 64 cols per pass; dwordx4 nontemporal stores
#pragma unroll
        for (int i = 0; i < 8; ++i) {
            int   rr = i * 4 + rsub;
            f32x4 v  = *(const f32x4*)&ldsw[rr * 64 + c4];
            if (nok) {
                long m = m_base + fm * 32 + rr;
                __builtin_nontemporal_store(
                    v, (f32x4*)(outp + m * (long)VV + nv));
            }
        }
    }
}

extern "C" void kernel_launch(void* const* d_in, const int* in_sizes, int n_in,
                              void* d_out, int out_size, void* d_ws, size_t ws_size,
                              hipStream_t stream) {
    const float* answer = (const float*)d_in[0];   // [640][768] f32
    const float* vocab  = (const float*)d_in[1];   // [30000][768] f32
    const float* W      = (const float*)d_in[2];   // [768][768] f32
    const float* bvec   = (const float*)d_in[3];   // [768] f32

    char* ws = (char*)d_ws;
    unsigned short* Wt_bf   = (unsigned short*)ws;                      // 1,179,648 B
    unsigned short* A2F     = (unsigned short*)(ws + 1179648);          //   983,040 B
    float*          cptr    = (float*)(ws + 1179648 + 983040);          //     2,560 B
    unsigned short* VF      = (unsigned short*)(ws + 2165248);          // 46,104,576 B

    // 1. Wt = W^T (bf16), c = answer @ b
    prep_small<<<304, 256, 0, stream>>>(W, answer, bvec, Wt_bf, cptr);

    // 2. A2F = answer @ W in fragment order (60 blocks) ∥ vocab -> VF (11256)
    gemm_a2<<<A2BLK + CVTBLK, 256, 0, stream>>>(answer, Wt_bf, A2F, vocab, VF);

    // 3. out[m][v] = sum_k A2F[m][k] * VF(v,k) + c[m]
    //    1200 blocks (25 idle), XCD-grouped, dataflow + store-path overhaul.
    gemm_big<<<1200, 256, 0, stream>>>(A2F, VF, cptr, (float*)d_out);
}